// Round 1
// baseline (382.233 us; speedup 1.0000x reference)
//
#include <hip/hip_runtime.h>

#define IMG 4

// ---- LeNet C3 sparse connectivity ----
__device__ __constant__ int C3_NCH[16]  = {3,3,3,3,3,3, 4,4,4,4,4,4,4,4,4, 6};
__device__ __constant__ int C3_WOFF[16] = {0,75,150,225,300,375,
                                           450,550,650,750,850,950,1050,1150,1250,
                                           1350};
__device__ __constant__ int C3_CH[16][6] = {
    {0,1,2,0,0,0},{1,2,3,0,0,0},{2,3,4,0,0,0},{3,4,5,0,0,0},{0,4,5,0,0,0},{0,1,5,0,0,0},
    {0,1,2,3,0,0},{1,2,3,4,0,0},{2,3,4,5,0,0},{0,3,4,5,0,0},{0,1,4,5,0,0},
    {0,1,2,5,0,0},{0,1,3,4,0,0},{1,2,4,5,0,0},{0,2,3,5,0,0},
    {0,1,2,3,4,5}
};

__device__ __forceinline__ float fast_tanh(float x) {
    // tanh(x) = 1 - 2/(e^{2x}+1); saturates to +/-1 for |x| large, no NaN.
    float e = __expf(2.0f * x);
    return 1.0f - 2.0f / (e + 1.0f);
}

// LDS layout (floats), all offsets multiple of 4 for float4 access:
//   x_s    [0      .. 4096)   4 images x 32x32
//   s2_s   [4096   .. 8800)   4 x 6x14x14
//   s4_s   [8800   .. 10400)  4 x 16x5x5
//   c5o_s  [10400  .. 10880)  4 x 120
//   f6_s   [10880  .. 11216)  4 x 84
//   c1w_s  [11216  .. 11368)  150 (+2 pad)
//   c1b_s  [11368  .. 11376)  6 (+2 pad)
//   c3w_s  [11376  .. 12876)  1500 compact (w3|w4|w6)
//   c3b_s  [12876  .. 12892)  16
#define SMEM_FLOATS 12892

__global__ __launch_bounds__(256) void lenet_fused(
    const float* __restrict__ x,
    const float* __restrict__ c1_w,  const float* __restrict__ c1_b,
    const float* __restrict__ c3_w3, const float* __restrict__ c3_b3,
    const float* __restrict__ c3_w4, const float* __restrict__ c3_b4,
    const float* __restrict__ c3_w6, const float* __restrict__ c3_b6,
    const float* __restrict__ c5_w,  const float* __restrict__ c5_b,
    const float* __restrict__ l1_w,  const float* __restrict__ l1_b,
    const float* __restrict__ l2_w,  const float* __restrict__ l2_b,
    float* __restrict__ out, int B)
{
    __shared__ __align__(16) float smem[SMEM_FLOATS];
    float* x_s   = smem;
    float* s2_s  = smem + 4096;
    float* s4_s  = smem + 8800;
    float* c5o_s = smem + 10400;
    float* f6_s  = smem + 10880;
    float* c1w_s = smem + 11216;
    float* c1b_s = smem + 11368;
    float* c3w_s = smem + 11376;
    float* c3b_s = smem + 12876;

    const int tid  = threadIdx.x;
    const int img0 = blockIdx.x * IMG;
    const int nimg = min(IMG, B - img0);
    if (nimg <= 0) return;

    // ---- stage weights into LDS ----
    for (int i = tid; i < 150; i += 256) c1w_s[i] = c1_w[i];
    if (tid < 6) c1b_s[tid] = c1_b[tid];
    for (int i = tid; i < 450; i += 256) c3w_s[i]        = c3_w3[i];
    for (int i = tid; i < 900; i += 256) c3w_s[450 + i]  = c3_w4[i];
    for (int i = tid; i < 150; i += 256) c3w_s[1350 + i] = c3_w6[i];
    if (tid < 6)        c3b_s[tid] = c3_b3[tid];
    else if (tid < 15)  c3b_s[tid] = c3_b4[tid - 6];
    else if (tid == 15) c3b_s[15]  = c3_b6[0];

    // ---- stage x into LDS (coalesced float4) ----
    {
        const float4* xg = (const float4*)(x + (size_t)img0 * 1024);
        float4* xs = (float4*)x_s;
        int n4 = nimg * 256;
        for (int i = tid; i < n4; i += 256) xs[i] = xg[i];
    }
    __syncthreads();

    // ---- C1 (5x5 conv) + tanh + 2x2 avgpool -> s2 [img][6][14][14] ----
    // work item = (img, c, pooled-row i, half h): 14 conv cols -> 7 pooled cols
    for (int it = tid; it < nimg * 168; it += 256) {
        int h   = it & 1;
        int t2  = it >> 1;
        int i   = t2 % 14;
        int t3  = t2 / 14;
        int c   = t3 % 6;
        int img = t3 / 6;
        const float* xb = x_s + img * 1024;
        float w[25];
        #pragma unroll
        for (int k = 0; k < 25; ++k) w[k] = c1w_s[c * 25 + k];
        float acc[2][14];
        #pragma unroll
        for (int a = 0; a < 2; ++a)
            #pragma unroll
            for (int j = 0; j < 14; ++j) acc[a][j] = 0.0f;
        const int col0 = 14 * h;
        #pragma unroll
        for (int xr = 0; xr < 6; ++xr) {
            float row[18];
            const float* rp = xb + (2 * i + xr) * 32 + col0;
            #pragma unroll
            for (int k = 0; k < 18; ++k) row[k] = rp[k];
            #pragma unroll
            for (int di = 0; di < 2; ++di) {
                const int u = xr - di;
                if (u >= 0 && u <= 4) {
                    #pragma unroll
                    for (int j = 0; j < 14; ++j)
                        #pragma unroll
                        for (int v = 0; v < 5; ++v)
                            acc[di][j] = fmaf(row[j + v], w[u * 5 + v], acc[di][j]);
                }
            }
        }
        const float b = c1b_s[c];
        float* o = s2_s + img * 1176 + c * 196 + i * 14 + 7 * h;
        #pragma unroll
        for (int j = 0; j < 7; ++j) {
            float t00 = fast_tanh(acc[0][2 * j]     + b);
            float t01 = fast_tanh(acc[0][2 * j + 1] + b);
            float t10 = fast_tanh(acc[1][2 * j]     + b);
            float t11 = fast_tanh(acc[1][2 * j + 1] + b);
            o[j] = 0.25f * (t00 + t01 + t10 + t11);
        }
    }
    __syncthreads();

    // ---- C3 sparse (5x5 conv over 3/4/6 maps) + tanh + pool -> s4 [img][16][5][5] ----
    // work item = (img, m, pooled-row i): 10 conv cols -> 5 pooled cols
    for (int it = tid; it < nimg * 80; it += 256) {
        int i   = it % 5;
        int t2  = it / 5;
        int m   = t2 % 16;
        int img = t2 / 16;
        const int n = C3_NCH[m];
        const float* wb = c3w_s + C3_WOFF[m];
        float acc[2][10];
        #pragma unroll
        for (int a = 0; a < 2; ++a)
            #pragma unroll
            for (int j = 0; j < 10; ++j) acc[a][j] = 0.0f;
        for (int cc = 0; cc < n; ++cc) {
            const int c = C3_CH[m][cc];
            float w[25];
            #pragma unroll
            for (int k = 0; k < 25; ++k) w[k] = wb[cc * 25 + k];
            const float* sb = s2_s + img * 1176 + c * 196;
            #pragma unroll
            for (int xr = 0; xr < 6; ++xr) {
                float row[14];
                const float* rp = sb + (2 * i + xr) * 14;
                #pragma unroll
                for (int k = 0; k < 14; ++k) row[k] = rp[k];
                #pragma unroll
                for (int di = 0; di < 2; ++di) {
                    const int u = xr - di;
                    if (u >= 0 && u <= 4) {
                        #pragma unroll
                        for (int j = 0; j < 10; ++j)
                            #pragma unroll
                            for (int v = 0; v < 5; ++v)
                                acc[di][j] = fmaf(row[j + v], w[u * 5 + v], acc[di][j]);
                    }
                }
            }
        }
        const float b = c3b_s[m];
        float* o = s4_s + img * 400 + m * 25 + i * 5;
        #pragma unroll
        for (int j = 0; j < 5; ++j) {
            float t00 = fast_tanh(acc[0][2 * j]     + b);
            float t01 = fast_tanh(acc[0][2 * j + 1] + b);
            float t10 = fast_tanh(acc[1][2 * j]     + b);
            float t11 = fast_tanh(acc[1][2 * j + 1] + b);
            o[j] = 0.25f * (t00 + t01 + t10 + t11);
        }
    }
    __syncthreads();

    // ---- C5: FC 400 -> 120, tanh. 2 outputs/thread, float4 streams ----
    for (int it = tid; it < nimg * 60; it += 256) {
        int op  = it % 60;
        int img = it / 60;
        int o0  = op * 2;
        const float4* wa = (const float4*)(c5_w + (size_t)o0 * 400);
        const float4* wb = (const float4*)(c5_w + (size_t)o0 * 400 + 400);
        const float4* sv = (const float4*)(s4_s + img * 400);
        float a0 = 0.0f, a1 = 0.0f;
        #pragma unroll 4
        for (int k = 0; k < 100; ++k) {
            float4 s = sv[k];
            float4 u = wa[k];
            float4 v = wb[k];
            a0 = fmaf(s.x, u.x, a0); a0 = fmaf(s.y, u.y, a0);
            a0 = fmaf(s.z, u.z, a0); a0 = fmaf(s.w, u.w, a0);
            a1 = fmaf(s.x, v.x, a1); a1 = fmaf(s.y, v.y, a1);
            a1 = fmaf(s.z, v.z, a1); a1 = fmaf(s.w, v.w, a1);
        }
        c5o_s[img * 120 + o0]     = fast_tanh(a0 + c5_b[o0]);
        c5o_s[img * 120 + o0 + 1] = fast_tanh(a1 + c5_b[o0 + 1]);
    }
    __syncthreads();

    // ---- F6: FC 120 -> 84, tanh ----
    for (int it = tid; it < nimg * 84; it += 256) {
        int o   = it % 84;
        int img = it / 84;
        const float4* wv = (const float4*)(l1_w + o * 120);
        const float4* cv = (const float4*)(c5o_s + img * 120);
        float a = 0.0f;
        #pragma unroll
        for (int k = 0; k < 30; ++k) {
            float4 u = wv[k];
            float4 s = cv[k];
            a = fmaf(s.x, u.x, a); a = fmaf(s.y, u.y, a);
            a = fmaf(s.z, u.z, a); a = fmaf(s.w, u.w, a);
        }
        f6_s[img * 84 + o] = fast_tanh(a + l1_b[o]);
    }
    __syncthreads();

    // ---- Output: FC 84 -> 10 (no tanh) ----
    for (int it = tid; it < nimg * 10; it += 256) {
        int o   = it % 10;
        int img = it / 10;
        const float4* wv = (const float4*)(l2_w + o * 84);
        const float4* fv = (const float4*)(f6_s + img * 84);
        float a = 0.0f;
        #pragma unroll
        for (int k = 0; k < 21; ++k) {
            float4 u = wv[k];
            float4 s = fv[k];
            a = fmaf(s.x, u.x, a); a = fmaf(s.y, u.y, a);
            a = fmaf(s.z, u.z, a); a = fmaf(s.w, u.w, a);
        }
        out[(size_t)(img0 + img) * 10 + o] = a + l2_b[o];
    }
}

extern "C" void kernel_launch(void* const* d_in, const int* in_sizes, int n_in,
                              void* d_out, int out_size, void* d_ws, size_t ws_size,
                              hipStream_t stream) {
    const float* x     = (const float*)d_in[0];
    const float* c1_w  = (const float*)d_in[1];
    const float* c1_b  = (const float*)d_in[2];
    const float* c3_w3 = (const float*)d_in[3];
    const float* c3_b3 = (const float*)d_in[4];
    const float* c3_w4 = (const float*)d_in[5];
    const float* c3_b4 = (const float*)d_in[6];
    const float* c3_w6 = (const float*)d_in[7];
    const float* c3_b6 = (const float*)d_in[8];
    const float* c5_w  = (const float*)d_in[9];
    const float* c5_b  = (const float*)d_in[10];
    const float* l1_w  = (const float*)d_in[11];
    const float* l1_b  = (const float*)d_in[12];
    const float* l2_w  = (const float*)d_in[13];
    const float* l2_b  = (const float*)d_in[14];
    float* out = (float*)d_out;

    const int B = in_sizes[0] / 1024;   // [B,1,32,32]
    const int grid = (B + IMG - 1) / IMG;
    lenet_fused<<<grid, 256, 0, stream>>>(
        x, c1_w, c1_b, c3_w3, c3_b3, c3_w4, c3_b4, c3_w6, c3_b6,
        c5_w, c5_b, l1_w, l1_b, l2_w, l2_b, out, B);
}

// Round 2
// 328.738 us; speedup vs baseline: 1.1627x; 1.1627x over previous
//
#include <hip/hip_runtime.h>

#define IMG 4
// Padded strides to break LDS bank aliasing (32 banks, stride%32 != 0).
#define XSTR  33                 // x row stride (33%32=1 -> row shifts bank by 1)
#define XIMG  (32 * XSTR)        // 1056 floats per image
#define S2STR 15                 // s2 row stride
#define S2MAP (14 * S2STR)       // 210
#define S2IMG (6 * S2MAP)        // 1260

// ---- LDS layout (floats) ----
// Region A [0..4224): phase1 = x (4 x 32 x 33)
//                     phase2+ = c3w[0..1500) | s4 @1504 (1600) | c5o @3104 (480) | f6 @3584 (336)
#define A_SIZE   (IMG * XIMG)        // 4224
#define S4_OFF   1504
#define C5O_OFF  3104
#define F6_OFF   3584
#define S2_OFF   A_SIZE              // 4224, size 4*1260 = 5040
#define C1W_OFF  (S2_OFF + IMG * S2IMG)   // 9264, size 150 (+2 pad)
#define C1B_OFF  (C1W_OFF + 152)     // 9416, size 6 (+2)
#define C3B_OFF  (C1B_OFF + 8)       // 9424, size 16
#define SMEM_FLOATS (C3B_OFF + 16)   // 9440 floats = 37760 B -> 4 blocks/CU

// ---- LeNet C3 sparse connectivity ----
__device__ __constant__ int C3_NCH[16]  = {3,3,3,3,3,3, 4,4,4,4,4,4,4,4,4, 6};
__device__ __constant__ int C3_WOFF[16] = {0,75,150,225,300,375,
                                           450,550,650,750,850,950,1050,1150,1250,
                                           1350};
__device__ __constant__ int C3_CH[16][6] = {
    {0,1,2,0,0,0},{1,2,3,0,0,0},{2,3,4,0,0,0},{3,4,5,0,0,0},{0,4,5,0,0,0},{0,1,5,0,0,0},
    {0,1,2,3,0,0},{1,2,3,4,0,0},{2,3,4,5,0,0},{0,3,4,5,0,0},{0,1,4,5,0,0},
    {0,1,2,5,0,0},{0,1,3,4,0,0},{1,2,4,5,0,0},{0,2,3,5,0,0},
    {0,1,2,3,4,5}
};

__device__ __forceinline__ float fast_tanh(float x) {
    // tanh(x) = 1 - 2/(e^{2x}+1); saturates to +/-1, no NaN.
    float e = __expf(2.0f * x);
    return 1.0f - 2.0f / (e + 1.0f);
}

__global__ __launch_bounds__(256, 4) void lenet_fused(
    const float* __restrict__ x,
    const float* __restrict__ c1_w,  const float* __restrict__ c1_b,
    const float* __restrict__ c3_w3, const float* __restrict__ c3_b3,
    const float* __restrict__ c3_w4, const float* __restrict__ c3_b4,
    const float* __restrict__ c3_w6, const float* __restrict__ c3_b6,
    const float* __restrict__ c5_w,  const float* __restrict__ c5_b,
    const float* __restrict__ l1_w,  const float* __restrict__ l1_b,
    const float* __restrict__ l2_w,  const float* __restrict__ l2_b,
    float* __restrict__ out, int B)
{
    __shared__ __align__(16) float smem[SMEM_FLOATS];
    float* x_s   = smem;                 // phase 1 only
    float* c3w_s = smem;                 // phase 2+ (aliases x_s)
    float* s4_s  = smem + S4_OFF;
    float* c5o_s = smem + C5O_OFF;
    float* f6_s  = smem + F6_OFF;
    float* s2_s  = smem + S2_OFF;
    float* c1w_s = smem + C1W_OFF;
    float* c1b_s = smem + C1B_OFF;
    float* c3b_s = smem + C3B_OFF;

    const int tid  = threadIdx.x;
    const int img0 = blockIdx.x * IMG;
    const int nimg = min(IMG, B - img0);
    if (nimg <= 0) return;

    // ---- prefetch c3 weights into registers (consumed after C1) ----
    float c3wr[6];
    const int c3base = tid * 6;
    #pragma unroll
    for (int j = 0; j < 6; ++j) {
        int idx = c3base + j;
        float v = 0.0f;
        if (idx < 450)        v = c3_w3[idx];
        else if (idx < 1350)  v = c3_w4[idx - 450];
        else if (idx < 1500)  v = c3_w6[idx - 1350];
        c3wr[j] = v;
    }

    // ---- stage small persistent weights ----
    for (int i = tid; i < 150; i += 256) c1w_s[i] = c1_w[i];
    if (tid < 6) c1b_s[tid] = c1_b[tid];
    if (tid < 6)        c3b_s[tid] = c3_b3[tid];
    else if (tid < 15)  c3b_s[tid] = c3_b4[tid - 6];
    else if (tid == 15) c3b_s[15]  = c3_b6[0];

    // ---- stage x into padded LDS (coalesced float4 global reads) ----
    {
        const float4* xg = (const float4*)(x + (size_t)img0 * 1024);
        const int n4 = nimg * 256;
        for (int i = tid; i < n4; i += 256) {
            float4 v = xg[i];
            int img = i >> 8, q = i & 255;
            int row = q >> 3, col4 = (q & 7) << 2;
            float* p = x_s + img * XIMG + row * XSTR + col4;
            p[0] = v.x; p[1] = v.y; p[2] = v.z; p[3] = v.w;
        }
    }
    __syncthreads();

    // ---- C1 (5x5 conv) + tanh + 2x2 avgpool -> s2 [img][6][14 x S2STR] ----
    // work item = (img, c, pooled-row i, half h): 14 conv cols -> 7 pooled cols
    for (int it = tid; it < nimg * 168; it += 256) {
        int h   = it & 1;
        int t2  = it >> 1;
        int i   = t2 % 14;
        int t3  = t2 / 14;
        int c   = t3 % 6;
        int img = t3 / 6;
        const float* xb = x_s + img * XIMG;
        float w[25];
        #pragma unroll
        for (int k = 0; k < 25; ++k) w[k] = c1w_s[c * 25 + k];
        float acc[2][14];
        #pragma unroll
        for (int a = 0; a < 2; ++a)
            #pragma unroll
            for (int j = 0; j < 14; ++j) acc[a][j] = 0.0f;
        const int col0 = 14 * h;
        #pragma unroll
        for (int xr = 0; xr < 6; ++xr) {
            float row[18];
            const float* rp = xb + (2 * i + xr) * XSTR + col0;
            #pragma unroll
            for (int k = 0; k < 18; ++k) row[k] = rp[k];
            #pragma unroll
            for (int di = 0; di < 2; ++di) {
                const int u = xr - di;
                if (u >= 0 && u <= 4) {
                    #pragma unroll
                    for (int j = 0; j < 14; ++j)
                        #pragma unroll
                        for (int v = 0; v < 5; ++v)
                            acc[di][j] = fmaf(row[j + v], w[u * 5 + v], acc[di][j]);
                }
            }
        }
        const float b = c1b_s[c];
        float* o = s2_s + img * S2IMG + c * S2MAP + i * S2STR + 7 * h;
        #pragma unroll
        for (int j = 0; j < 7; ++j) {
            float t00 = fast_tanh(acc[0][2 * j]     + b);
            float t01 = fast_tanh(acc[0][2 * j + 1] + b);
            float t10 = fast_tanh(acc[1][2 * j]     + b);
            float t11 = fast_tanh(acc[1][2 * j + 1] + b);
            o[j] = 0.25f * (t00 + t01 + t10 + t11);
        }
    }
    __syncthreads();

    // ---- x_s is dead: store prefetched c3 weights into region A ----
    #pragma unroll
    for (int j = 0; j < 6; ++j) {
        int idx = c3base + j;
        if (idx < 1500) c3w_s[idx] = c3wr[j];
    }
    __syncthreads();

    // ---- C3 sparse conv + tanh + pool -> s4 [img][16][5][5] ----
    for (int it = tid; it < nimg * 80; it += 256) {
        int i   = it % 5;
        int t2  = it / 5;
        int m   = t2 % 16;
        int img = t2 / 16;
        const int n = C3_NCH[m];
        const float* wb = c3w_s + C3_WOFF[m];
        float acc[2][10];
        #pragma unroll
        for (int a = 0; a < 2; ++a)
            #pragma unroll
            for (int j = 0; j < 10; ++j) acc[a][j] = 0.0f;
        for (int cc = 0; cc < n; ++cc) {
            const int c = C3_CH[m][cc];
            float w[25];
            #pragma unroll
            for (int k = 0; k < 25; ++k) w[k] = wb[cc * 25 + k];
            const float* sb = s2_s + img * S2IMG + c * S2MAP;
            #pragma unroll
            for (int xr = 0; xr < 6; ++xr) {
                float row[14];
                const float* rp = sb + (2 * i + xr) * S2STR;
                #pragma unroll
                for (int k = 0; k < 14; ++k) row[k] = rp[k];
                #pragma unroll
                for (int di = 0; di < 2; ++di) {
                    const int u = xr - di;
                    if (u >= 0 && u <= 4) {
                        #pragma unroll
                        for (int j = 0; j < 10; ++j)
                            #pragma unroll
                            for (int v = 0; v < 5; ++v)
                                acc[di][j] = fmaf(row[j + v], w[u * 5 + v], acc[di][j]);
                    }
                }
            }
        }
        const float b = c3b_s[m];
        float* o = s4_s + img * 400 + m * 25 + i * 5;
        #pragma unroll
        for (int j = 0; j < 5; ++j) {
            float t00 = fast_tanh(acc[0][2 * j]     + b);
            float t01 = fast_tanh(acc[0][2 * j + 1] + b);
            float t10 = fast_tanh(acc[1][2 * j]     + b);
            float t11 = fast_tanh(acc[1][2 * j + 1] + b);
            o[j] = 0.25f * (t00 + t01 + t10 + t11);
        }
    }
    __syncthreads();

    // ---- C5: FC 400 -> 120, tanh. 2 outputs/thread, float4 streams ----
    for (int it = tid; it < nimg * 60; it += 256) {
        int op  = it % 60;
        int img = it / 60;
        int o0  = op * 2;
        const float4* wa = (const float4*)(c5_w + (size_t)o0 * 400);
        const float4* wb = (const float4*)(c5_w + (size_t)o0 * 400 + 400);
        const float4* sv = (const float4*)(s4_s + img * 400);
        float a0 = 0.0f, a1 = 0.0f;
        #pragma unroll 4
        for (int k = 0; k < 100; ++k) {
            float4 s = sv[k];
            float4 u = wa[k];
            float4 v = wb[k];
            a0 = fmaf(s.x, u.x, a0); a0 = fmaf(s.y, u.y, a0);
            a0 = fmaf(s.z, u.z, a0); a0 = fmaf(s.w, u.w, a0);
            a1 = fmaf(s.x, v.x, a1); a1 = fmaf(s.y, v.y, a1);
            a1 = fmaf(s.z, v.z, a1); a1 = fmaf(s.w, v.w, a1);
        }
        c5o_s[img * 120 + o0]     = fast_tanh(a0 + c5_b[o0]);
        c5o_s[img * 120 + o0 + 1] = fast_tanh(a1 + c5_b[o0 + 1]);
    }
    __syncthreads();

    // ---- F6: FC 120 -> 84, tanh ----
    for (int it = tid; it < nimg * 84; it += 256) {
        int o   = it % 84;
        int img = it / 84;
        const float4* wv = (const float4*)(l1_w + o * 120);
        const float4* cv = (const float4*)(c5o_s + img * 120);
        float a = 0.0f;
        #pragma unroll
        for (int k = 0; k < 30; ++k) {
            float4 u = wv[k];
            float4 s = cv[k];
            a = fmaf(s.x, u.x, a); a = fmaf(s.y, u.y, a);
            a = fmaf(s.z, u.z, a); a = fmaf(s.w, u.w, a);
        }
        f6_s[img * 84 + o] = fast_tanh(a + l1_b[o]);
    }
    __syncthreads();

    // ---- Output: FC 84 -> 10 (no tanh) ----
    for (int it = tid; it < nimg * 10; it += 256) {
        int o   = it % 10;
        int img = it / 10;
        const float4* wv = (const float4*)(l2_w + o * 84);
        const float4* fv = (const float4*)(f6_s + img * 84);
        float a = 0.0f;
        #pragma unroll
        for (int k = 0; k < 21; ++k) {
            float4 u = wv[k];
            float4 s = fv[k];
            a = fmaf(s.x, u.x, a); a = fmaf(s.y, u.y, a);
            a = fmaf(s.z, u.z, a); a = fmaf(s.w, u.w, a);
        }
        out[(size_t)(img0 + img) * 10 + o] = a + l2_b[o];
    }
}

extern "C" void kernel_launch(void* const* d_in, const int* in_sizes, int n_in,
                              void* d_out, int out_size, void* d_ws, size_t ws_size,
                              hipStream_t stream) {
    const float* x     = (const float*)d_in[0];
    const float* c1_w  = (const float*)d_in[1];
    const float* c1_b  = (const float*)d_in[2];
    const float* c3_w3 = (const float*)d_in[3];
    const float* c3_b3 = (const float*)d_in[4];
    const float* c3_w4 = (const float*)d_in[5];
    const float* c3_b4 = (const float*)d_in[6];
    const float* c3_w6 = (const float*)d_in[7];
    const float* c3_b6 = (const float*)d_in[8];
    const float* c5_w  = (const float*)d_in[9];
    const float* c5_b  = (const float*)d_in[10];
    const float* l1_w  = (const float*)d_in[11];
    const float* l1_b  = (const float*)d_in[12];
    const float* l2_w  = (const float*)d_in[13];
    const float* l2_b  = (const float*)d_in[14];
    float* out = (float*)d_out;

    const int B = in_sizes[0] / 1024;   // [B,1,32,32]
    const int grid = (B + IMG - 1) / IMG;
    lenet_fused<<<grid, 256, 0, stream>>>(
        x, c1_w, c1_b, c3_w3, c3_b3, c3_w4, c3_b4, c3_w6, c3_b6,
        c5_w, c5_b, l1_w, l1_b, l2_w, l2_b, out, B);
}